// Round 1
// baseline (466.500 us; speedup 1.0000x reference)
//
#include <hip/hip_runtime.h>

#define HIDDEN 2048
#define INTER  5632
#define TOKENS 4096

#define BM 128
#define BN 128
#define BK 64

using bf16x8 = __attribute__((ext_vector_type(8))) __bf16;
using f32x4  = __attribute__((ext_vector_type(4))) float;

// fp32 -> bf16 round-to-nearest-even (bit-level, avoids __hip_bfloat16 union issues)
__device__ __forceinline__ unsigned short f2bf(float f) {
    unsigned int u = __float_as_uint(f);
    u += 0x7FFFu + ((u >> 16) & 1u);
    return (unsigned short)(u >> 16);
}

// ---------------- cast x fp32 -> bf16, 8 elems/thread ----------------
__global__ __launch_bounds__(256) void cast_x_kernel(const float* __restrict__ x,
                                                     unsigned short* __restrict__ xb) {
    int t = blockIdx.x * 256 + threadIdx.x;
    const float4* x4 = (const float4*)x;
    float4 a = x4[2 * t];
    float4 b = x4[2 * t + 1];
    uint4 o;
    o.x = f2bf(a.x) | ((unsigned int)f2bf(a.y) << 16);
    o.y = f2bf(a.z) | ((unsigned int)f2bf(a.w) << 16);
    o.z = f2bf(b.x) | ((unsigned int)f2bf(b.y) << 16);
    o.w = f2bf(b.z) | ((unsigned int)f2bf(b.w) << 16);
    ((uint4*)xb)[t] = o;
}

// ------------- dequant: one thread per index (8 weights) -------------
// idx: [nrows, ncol8] int32; cb: [4096, 8] f32; out w: [nrows, ncol8*8] bf16
__global__ __launch_bounds__(256) void dequant_kernel(const int* __restrict__ idx,
                                                      const float* __restrict__ cb,
                                                      const float* __restrict__ scale,
                                                      unsigned short* __restrict__ w,
                                                      int ncol8) {
    int t = blockIdx.x * 256 + threadIdx.x;
    int row = t / ncol8;
    int id = idx[t];
    float s = scale[row];
    const float4* c4 = (const float4*)(cb + ((size_t)id << 3));
    float4 a = c4[0];
    float4 b = c4[1];
    uint4 o;
    o.x = f2bf(a.x * s) | ((unsigned int)f2bf(a.y * s) << 16);
    o.y = f2bf(a.z * s) | ((unsigned int)f2bf(a.w * s) << 16);
    o.z = f2bf(b.x * s) | ((unsigned int)f2bf(b.y * s) << 16);
    o.w = f2bf(b.z * s) | ((unsigned int)f2bf(b.w * s) << 16);
    ((uint4*)w)[t] = o;
}

// ---------------- GEMM1: H = silu(X Wg^T) * (X Wu^T), bf16 out ----------------
// X: [TOKENS, HIDDEN] bf16, Wg/Wu: [INTER, HIDDEN] bf16, H: [TOKENS, INTER] bf16
__global__ __launch_bounds__(256, 2) void gemm1_kernel(const unsigned short* __restrict__ X,
                                                       const unsigned short* __restrict__ Wg,
                                                       const unsigned short* __restrict__ Wu,
                                                       unsigned short* __restrict__ H) {
    __shared__ unsigned short As[BM * BK];
    __shared__ unsigned short Bgs[BN * BK];
    __shared__ unsigned short Bus[BN * BK];

    const int tid  = threadIdx.x;
    const int lane = tid & 63;
    const int wave = tid >> 6;
    const int m0 = blockIdx.x * BM;
    const int n0 = blockIdx.y * BN;

    // staging: thread covers (row = i*32 + tid/8, col = (tid%8)*8), 16B per lane
    const int srow = tid >> 3;
    const int scol = (tid & 7) << 3;

    // compute: wave -> 64x64 quadrant; 4x4 grid of 16x16x32 MFMAs
    const int wr = wave >> 1;
    const int wc = wave & 1;
    const int ln15 = lane & 15;
    const int lq = lane >> 4;

    f32x4 accg[4][4], accu[4][4];
    const f32x4 z = {0.f, 0.f, 0.f, 0.f};
    for (int i = 0; i < 4; ++i)
        for (int j = 0; j < 4; ++j) { accg[i][j] = z; accu[i][j] = z; }

    for (int kt = 0; kt < HIDDEN / BK; ++kt) {
        const int k0 = kt * BK;
        __syncthreads();
#pragma unroll
        for (int i = 0; i < 4; ++i) {
            const int r = i * 32 + srow;
            __builtin_amdgcn_global_load_lds(
                (__attribute__((address_space(1))) void*)(X + (size_t)(m0 + r) * HIDDEN + k0 + scol),
                (__attribute__((address_space(3))) void*)(As + r * BK + scol), 16, 0, 0);
            __builtin_amdgcn_global_load_lds(
                (__attribute__((address_space(1))) void*)(Wg + (size_t)(n0 + r) * HIDDEN + k0 + scol),
                (__attribute__((address_space(3))) void*)(Bgs + r * BK + scol), 16, 0, 0);
            __builtin_amdgcn_global_load_lds(
                (__attribute__((address_space(1))) void*)(Wu + (size_t)(n0 + r) * HIDDEN + k0 + scol),
                (__attribute__((address_space(3))) void*)(Bus + r * BK + scol), 16, 0, 0);
        }
        __syncthreads();
#pragma unroll
        for (int ks = 0; ks < 2; ++ks) {
            const int kofs = ks * 32 + lq * 8;
            bf16x8 af[4], bg[4], bu[4];
#pragma unroll
            for (int im = 0; im < 4; ++im)
                af[im] = *(const bf16x8*)(As + (wr * 64 + im * 16 + ln15) * BK + kofs);
#pragma unroll
            for (int in = 0; in < 4; ++in) {
                bg[in] = *(const bf16x8*)(Bgs + (wc * 64 + in * 16 + ln15) * BK + kofs);
                bu[in] = *(const bf16x8*)(Bus + (wc * 64 + in * 16 + ln15) * BK + kofs);
            }
#pragma unroll
            for (int im = 0; im < 4; ++im)
#pragma unroll
                for (int in = 0; in < 4; ++in) {
                    accg[im][in] = __builtin_amdgcn_mfma_f32_16x16x32_bf16(af[im], bg[in], accg[im][in], 0, 0, 0);
                    accu[im][in] = __builtin_amdgcn_mfma_f32_16x16x32_bf16(af[im], bu[in], accu[im][in], 0, 0, 0);
                }
        }
    }

    // epilogue: h = silu(g) * u   (C/D layout: col=lane&15, row=lq*4+reg)
#pragma unroll
    for (int im = 0; im < 4; ++im)
#pragma unroll
        for (int in = 0; in < 4; ++in) {
            const int row = m0 + wr * 64 + im * 16 + lq * 4;
            const int col = n0 + wc * 64 + in * 16 + ln15;
#pragma unroll
            for (int r = 0; r < 4; ++r) {
                float g = accg[im][in][r];
                float u = accu[im][in][r];
                float h = g * (1.0f / (1.0f + __expf(-g))) * u;
                H[(size_t)(row + r) * INTER + col] = f2bf(h);
            }
        }
}

// ---------------- GEMM2: Out = H Wd^T, fp32 out ----------------
// H: [TOKENS, INTER] bf16, Wd: [HIDDEN, INTER] bf16, Out: [TOKENS, HIDDEN] f32
__global__ __launch_bounds__(256, 2) void gemm2_kernel(const unsigned short* __restrict__ Hin,
                                                       const unsigned short* __restrict__ Wd,
                                                       float* __restrict__ Out) {
    __shared__ unsigned short As[BM * BK];
    __shared__ unsigned short Bs[BN * BK];

    const int tid  = threadIdx.x;
    const int lane = tid & 63;
    const int wave = tid >> 6;
    const int m0 = blockIdx.x * BM;
    const int n0 = blockIdx.y * BN;

    const int srow = tid >> 3;
    const int scol = (tid & 7) << 3;

    const int wr = wave >> 1;
    const int wc = wave & 1;
    const int ln15 = lane & 15;
    const int lq = lane >> 4;

    f32x4 acc[4][4];
    const f32x4 z = {0.f, 0.f, 0.f, 0.f};
    for (int i = 0; i < 4; ++i)
        for (int j = 0; j < 4; ++j) acc[i][j] = z;

    for (int kt = 0; kt < INTER / BK; ++kt) {
        const int k0 = kt * BK;
        __syncthreads();
#pragma unroll
        for (int i = 0; i < 4; ++i) {
            const int r = i * 32 + srow;
            __builtin_amdgcn_global_load_lds(
                (__attribute__((address_space(1))) void*)(Hin + (size_t)(m0 + r) * INTER + k0 + scol),
                (__attribute__((address_space(3))) void*)(As + r * BK + scol), 16, 0, 0);
            __builtin_amdgcn_global_load_lds(
                (__attribute__((address_space(1))) void*)(Wd + (size_t)(n0 + r) * INTER + k0 + scol),
                (__attribute__((address_space(3))) void*)(Bs + r * BK + scol), 16, 0, 0);
        }
        __syncthreads();
#pragma unroll
        for (int ks = 0; ks < 2; ++ks) {
            const int kofs = ks * 32 + lq * 8;
            bf16x8 af[4], bf[4];
#pragma unroll
            for (int im = 0; im < 4; ++im)
                af[im] = *(const bf16x8*)(As + (wr * 64 + im * 16 + ln15) * BK + kofs);
#pragma unroll
            for (int in = 0; in < 4; ++in)
                bf[in] = *(const bf16x8*)(Bs + (wc * 64 + in * 16 + ln15) * BK + kofs);
#pragma unroll
            for (int im = 0; im < 4; ++im)
#pragma unroll
                for (int in = 0; in < 4; ++in)
                    acc[im][in] = __builtin_amdgcn_mfma_f32_16x16x32_bf16(af[im], bf[in], acc[im][in], 0, 0, 0);
        }
    }

#pragma unroll
    for (int im = 0; im < 4; ++im)
#pragma unroll
        for (int in = 0; in < 4; ++in) {
            const int row = m0 + wr * 64 + im * 16 + lq * 4;
            const int col = n0 + wc * 64 + in * 16 + ln15;
#pragma unroll
            for (int r = 0; r < 4; ++r)
                Out[(size_t)(row + r) * HIDDEN + col] = acc[im][in][r];
        }
}

extern "C" void kernel_launch(void* const* d_in, const int* in_sizes, int n_in,
                              void* d_out, int out_size, void* d_ws, size_t ws_size,
                              hipStream_t stream) {
    (void)in_sizes; (void)n_in; (void)out_size; (void)ws_size;

    const float* x   = (const float*)d_in[0];
    const float* cbg = (const float*)d_in[1];
    const int*   ig  = (const int*)d_in[2];
    const float* sg  = (const float*)d_in[3];
    const float* cbu = (const float*)d_in[4];
    const int*   iu  = (const int*)d_in[5];
    const float* su  = (const float*)d_in[6];
    const float* cbd = (const float*)d_in[7];
    const int*   idn = (const int*)d_in[8];
    const float* sd  = (const float*)d_in[9];
    float* out = (float*)d_out;

    // workspace layout (all 16B aligned); total = 132,120,576 bytes
    char* p = (char*)d_ws;
    unsigned short* Xb = (unsigned short*)p; p += (size_t)TOKENS * HIDDEN * 2;
    unsigned short* Wg = (unsigned short*)p; p += (size_t)INTER * HIDDEN * 2;
    unsigned short* Wu = (unsigned short*)p; p += (size_t)INTER * HIDDEN * 2;
    unsigned short* Wd = (unsigned short*)p; p += (size_t)HIDDEN * INTER * 2;
    unsigned short* H  = (unsigned short*)p; p += (size_t)TOKENS * INTER * 2;

    cast_x_kernel<<<dim3(TOKENS * HIDDEN / 8 / 256), dim3(256), 0, stream>>>(x, Xb);
    // gate: 5632 rows x 256 idx-cols = 1,441,792 idx -> 5632 blocks
    dequant_kernel<<<dim3(INTER * (HIDDEN / 8) / 256), dim3(256), 0, stream>>>(ig, cbg, sg, Wg, HIDDEN / 8);
    dequant_kernel<<<dim3(INTER * (HIDDEN / 8) / 256), dim3(256), 0, stream>>>(iu, cbu, su, Wu, HIDDEN / 8);
    // down: 2048 rows x 704 idx-cols = 1,441,792 idx -> 5632 blocks
    dequant_kernel<<<dim3(HIDDEN * (INTER / 8) / 256), dim3(256), 0, stream>>>(idn, cbd, sd, Wd, INTER / 8);

    gemm1_kernel<<<dim3(TOKENS / BM, INTER / BN), dim3(256), 0, stream>>>(Xb, Wg, Wu, H);
    gemm2_kernel<<<dim3(TOKENS / BM, HIDDEN / BN), dim3(256), 0, stream>>>(H, Wd, out);
}

// Round 2
// 394.664 us; speedup vs baseline: 1.1820x; 1.1820x over previous
//
#include <hip/hip_runtime.h>

#define HIDDEN 2048
#define INTER  5632
#define TOKENS 4096

#define BM 128
#define BN 128
#define BK 64

using bf16x8 = __attribute__((ext_vector_type(8))) __bf16;
using f32x4  = __attribute__((ext_vector_type(4))) float;

// fp32 -> bf16 round-to-nearest-even
__device__ __forceinline__ unsigned short f2bf(float f) {
    unsigned int u = __float_as_uint(f);
    u += 0x7FFFu + ((u >> 16) & 1u);
    return (unsigned short)(u >> 16);
}

// ---------------- fused prep: cast x + dequant 3 weight mats ----------------
// grid = 4096 (cast) + 5632 (gate) + 5632 (up) + 5632 (down) blocks of 256
__global__ __launch_bounds__(256) void prep_kernel(
        const float* __restrict__ x, unsigned short* __restrict__ xb,
        const int* __restrict__ ig, const float* __restrict__ cbg,
        const float* __restrict__ sg, unsigned short* __restrict__ wg,
        const int* __restrict__ iu, const float* __restrict__ cbu,
        const float* __restrict__ su, unsigned short* __restrict__ wu,
        const int* __restrict__ idn, const float* __restrict__ cbd,
        const float* __restrict__ sd, unsigned short* __restrict__ wd) {
    int b = blockIdx.x;
    if (b < 4096) {
        int t = b * 256 + threadIdx.x;
        const float4* x4 = (const float4*)x;
        float4 a = x4[2 * t];
        float4 c = x4[2 * t + 1];
        uint4 o;
        o.x = f2bf(a.x) | ((unsigned int)f2bf(a.y) << 16);
        o.y = f2bf(a.z) | ((unsigned int)f2bf(a.w) << 16);
        o.z = f2bf(c.x) | ((unsigned int)f2bf(c.y) << 16);
        o.w = f2bf(c.z) | ((unsigned int)f2bf(c.w) << 16);
        ((uint4*)xb)[t] = o;
        return;
    }
    const int* idx; const float* cb; const float* scale; unsigned short* w; int ncol8;
    if (b < 4096 + 5632)      { b -= 4096;         idx = ig;  cb = cbg; scale = sg; w = wg; ncol8 = HIDDEN / 8; }
    else if (b < 4096 + 11264){ b -= 4096 + 5632;  idx = iu;  cb = cbu; scale = su; w = wu; ncol8 = HIDDEN / 8; }
    else                      { b -= 4096 + 11264; idx = idn; cb = cbd; scale = sd; w = wd; ncol8 = INTER / 8; }
    int t = b * 256 + threadIdx.x;
    int row = t / ncol8;
    int id = idx[t];
    float s = scale[row];
    const float4* c4 = (const float4*)(cb + ((size_t)id << 3));
    float4 a = c4[0];
    float4 c = c4[1];
    uint4 o;
    o.x = f2bf(a.x * s) | ((unsigned int)f2bf(a.y * s) << 16);
    o.y = f2bf(a.z * s) | ((unsigned int)f2bf(a.w * s) << 16);
    o.z = f2bf(c.x * s) | ((unsigned int)f2bf(c.y * s) << 16);
    o.w = f2bf(c.z * s) | ((unsigned int)f2bf(c.w * s) << 16);
    ((uint4*)w)[t] = o;
}

// XOR-swizzled LDS layout: physical 16B chunk p of row r holds logical chunk
// p ^ (r & 7).  Staging LDS dest stays lane-contiguous (global_load_lds
// constraint); the swizzle is applied to the GLOBAL source column instead.

// ---------------- GEMM1: H = silu(X Wg^T) * (X Wu^T), bf16 out ----------------
__global__ __launch_bounds__(256, 2) void gemm1_kernel(const unsigned short* __restrict__ X,
                                                       const unsigned short* __restrict__ Wg,
                                                       const unsigned short* __restrict__ Wu,
                                                       unsigned short* __restrict__ H) {
    __shared__ unsigned short As[BM * BK];
    __shared__ unsigned short Bgs[BN * BK];
    __shared__ unsigned short Bus[BN * BK];

    const int tid  = threadIdx.x;
    const int lane = tid & 63;
    const int wave = tid >> 6;
    const int m0 = blockIdx.x * BM;
    const int n0 = blockIdx.y * BN;

    // staging: thread covers (row = i*32 + tid/8), LDS phys chunk = tid&7 (contiguous),
    // global logical chunk = (tid&7) ^ (row&7);  row&7 == (tid>>3)&7 for all i.
    const int srow = tid >> 3;
    const int scol = (tid & 7) << 3;                       // LDS phys halfword offset
    const int gcol = (((tid & 7) ^ (srow & 7))) << 3;      // swizzled global halfword offset

    const int wr = wave >> 1;
    const int wc = wave & 1;
    const int ln15 = lane & 15;
    const int lq = lane >> 4;
    const int swr = ln15 & 7;                              // fragment-row swizzle key

    f32x4 accg[4][4], accu[4][4];
    const f32x4 z = {0.f, 0.f, 0.f, 0.f};
    for (int i = 0; i < 4; ++i)
        for (int j = 0; j < 4; ++j) { accg[i][j] = z; accu[i][j] = z; }

    for (int kt = 0; kt < HIDDEN / BK; ++kt) {
        const int k0 = kt * BK;
        __syncthreads();
#pragma unroll
        for (int i = 0; i < 4; ++i) {
            const int r = i * 32 + srow;
            __builtin_amdgcn_global_load_lds(
                (__attribute__((address_space(1))) void*)(X + (size_t)(m0 + r) * HIDDEN + k0 + gcol),
                (__attribute__((address_space(3))) void*)(As + r * BK + scol), 16, 0, 0);
            __builtin_amdgcn_global_load_lds(
                (__attribute__((address_space(1))) void*)(Wg + (size_t)(n0 + r) * HIDDEN + k0 + gcol),
                (__attribute__((address_space(3))) void*)(Bgs + r * BK + scol), 16, 0, 0);
            __builtin_amdgcn_global_load_lds(
                (__attribute__((address_space(1))) void*)(Wu + (size_t)(n0 + r) * HIDDEN + k0 + gcol),
                (__attribute__((address_space(3))) void*)(Bus + r * BK + scol), 16, 0, 0);
        }
        __syncthreads();
#pragma unroll
        for (int ks = 0; ks < 2; ++ks) {
            bf16x8 af[4], bg[4], bu[4];
            const int pofs = (((ks * 4 + lq) ^ swr)) << 3; // swizzled phys halfword offset
#pragma unroll
            for (int im = 0; im < 4; ++im)
                af[im] = *(const bf16x8*)(As + (wr * 64 + im * 16 + ln15) * BK + pofs);
#pragma unroll
            for (int in = 0; in < 4; ++in) {
                bg[in] = *(const bf16x8*)(Bgs + (wc * 64 + in * 16 + ln15) * BK + pofs);
                bu[in] = *(const bf16x8*)(Bus + (wc * 64 + in * 16 + ln15) * BK + pofs);
            }
#pragma unroll
            for (int im = 0; im < 4; ++im)
#pragma unroll
                for (int in = 0; in < 4; ++in) {
                    accg[im][in] = __builtin_amdgcn_mfma_f32_16x16x32_bf16(af[im], bg[in], accg[im][in], 0, 0, 0);
                    accu[im][in] = __builtin_amdgcn_mfma_f32_16x16x32_bf16(af[im], bu[in], accu[im][in], 0, 0, 0);
                }
        }
    }

#pragma unroll
    for (int im = 0; im < 4; ++im)
#pragma unroll
        for (int in = 0; in < 4; ++in) {
            const int row = m0 + wr * 64 + im * 16 + lq * 4;
            const int col = n0 + wc * 64 + in * 16 + ln15;
#pragma unroll
            for (int r = 0; r < 4; ++r) {
                float g = accg[im][in][r];
                float u = accu[im][in][r];
                float h = g * (1.0f / (1.0f + __expf(-g))) * u;
                H[(size_t)(row + r) * INTER + col] = f2bf(h);
            }
        }
}

// ---------------- GEMM2: Out = H Wd^T, fp32 out ----------------
__global__ __launch_bounds__(256, 2) void gemm2_kernel(const unsigned short* __restrict__ Hin,
                                                       const unsigned short* __restrict__ Wd,
                                                       float* __restrict__ Out) {
    __shared__ unsigned short As[BM * BK];
    __shared__ unsigned short Bs[BN * BK];

    const int tid  = threadIdx.x;
    const int lane = tid & 63;
    const int wave = tid >> 6;
    const int m0 = blockIdx.x * BM;
    const int n0 = blockIdx.y * BN;

    const int srow = tid >> 3;
    const int scol = (tid & 7) << 3;
    const int gcol = (((tid & 7) ^ (srow & 7))) << 3;

    const int wr = wave >> 1;
    const int wc = wave & 1;
    const int ln15 = lane & 15;
    const int lq = lane >> 4;
    const int swr = ln15 & 7;

    f32x4 acc[4][4];
    const f32x4 z = {0.f, 0.f, 0.f, 0.f};
    for (int i = 0; i < 4; ++i)
        for (int j = 0; j < 4; ++j) acc[i][j] = z;

    for (int kt = 0; kt < INTER / BK; ++kt) {
        const int k0 = kt * BK;
        __syncthreads();
#pragma unroll
        for (int i = 0; i < 4; ++i) {
            const int r = i * 32 + srow;
            __builtin_amdgcn_global_load_lds(
                (__attribute__((address_space(1))) void*)(Hin + (size_t)(m0 + r) * INTER + k0 + gcol),
                (__attribute__((address_space(3))) void*)(As + r * BK + scol), 16, 0, 0);
            __builtin_amdgcn_global_load_lds(
                (__attribute__((address_space(1))) void*)(Wd + (size_t)(n0 + r) * INTER + k0 + gcol),
                (__attribute__((address_space(3))) void*)(Bs + r * BK + scol), 16, 0, 0);
        }
        __syncthreads();
#pragma unroll
        for (int ks = 0; ks < 2; ++ks) {
            bf16x8 af[4], bf[4];
            const int pofs = (((ks * 4 + lq) ^ swr)) << 3;
#pragma unroll
            for (int im = 0; im < 4; ++im)
                af[im] = *(const bf16x8*)(As + (wr * 64 + im * 16 + ln15) * BK + pofs);
#pragma unroll
            for (int in = 0; in < 4; ++in)
                bf[in] = *(const bf16x8*)(Bs + (wc * 64 + in * 16 + ln15) * BK + pofs);
#pragma unroll
            for (int im = 0; im < 4; ++im)
#pragma unroll
                for (int in = 0; in < 4; ++in)
                    acc[im][in] = __builtin_amdgcn_mfma_f32_16x16x32_bf16(af[im], bf[in], acc[im][in], 0, 0, 0);
        }
    }

#pragma unroll
    for (int im = 0; im < 4; ++im)
#pragma unroll
        for (int in = 0; in < 4; ++in) {
            const int row = m0 + wr * 64 + im * 16 + lq * 4;
            const int col = n0 + wc * 64 + in * 16 + ln15;
#pragma unroll
            for (int r = 0; r < 4; ++r)
                Out[(size_t)(row + r) * HIDDEN + col] = acc[im][in][r];
        }
}

extern "C" void kernel_launch(void* const* d_in, const int* in_sizes, int n_in,
                              void* d_out, int out_size, void* d_ws, size_t ws_size,
                              hipStream_t stream) {
    (void)in_sizes; (void)n_in; (void)out_size; (void)ws_size;

    const float* x   = (const float*)d_in[0];
    const float* cbg = (const float*)d_in[1];
    const int*   ig  = (const int*)d_in[2];
    const float* sg  = (const float*)d_in[3];
    const float* cbu = (const float*)d_in[4];
    const int*   iu  = (const int*)d_in[5];
    const float* su  = (const float*)d_in[6];
    const float* cbd = (const float*)d_in[7];
    const int*   idn = (const int*)d_in[8];
    const float* sd  = (const float*)d_in[9];
    float* out = (float*)d_out;

    char* p = (char*)d_ws;
    unsigned short* Xb = (unsigned short*)p; p += (size_t)TOKENS * HIDDEN * 2;
    unsigned short* Wg = (unsigned short*)p; p += (size_t)INTER * HIDDEN * 2;
    unsigned short* Wu = (unsigned short*)p; p += (size_t)INTER * HIDDEN * 2;
    unsigned short* Wd = (unsigned short*)p; p += (size_t)HIDDEN * INTER * 2;
    unsigned short* H  = (unsigned short*)p; p += (size_t)TOKENS * INTER * 2;

    // 4096 cast blocks + 3*5632 dequant blocks
    prep_kernel<<<dim3(4096 + 3 * 5632), dim3(256), 0, stream>>>(
        x, Xb, ig, cbg, sg, Wg, iu, cbu, su, Wu, idn, cbd, sd, Wd);

    gemm1_kernel<<<dim3(TOKENS / BM, INTER / BN), dim3(256), 0, stream>>>(Xb, Wg, Wu, H);
    gemm2_kernel<<<dim3(TOKENS / BM, HIDDEN / BN), dim3(256), 0, stream>>>(H, Wd, out);
}